// Round 10
// baseline (96.567 us; speedup 1.0000x reference)
//
#include <hip/hip_runtime.h>

#define N_NODES 50000
#define N_EDGES 600000
#define F 128
#define BCAP 64   // bucket capacity (max degree ~30 for Poisson(12))

typedef __attribute__((ext_vector_type(8))) short bf16x8;
typedef __attribute__((ext_vector_type(4))) float f32x4;

// bf16 helpers (round-to-nearest-even)
__device__ inline unsigned short bf16rn(float f) {
  unsigned u = __float_as_uint(f);
  return (unsigned short)((u + 0x7FFFu + ((u >> 16) & 1u)) >> 16);
}
__device__ inline float bflo(unsigned u) { return __uint_as_float(u << 16); }
__device__ inline float bfhi(unsigned u) { return __uint_as_float(u & 0xFFFF0000u); }

// ---------- init: zero cnt + W1 -> bf16 Wt[n][k] + zero sentinel rows ----------
__global__ __launch_bounds__(256) void k_init(int* __restrict__ cnt, const float* __restrict__ W,
                                              ushort* __restrict__ wt, ushort* __restrict__ h,
                                              float* __restrict__ h2) {
  int i = blockIdx.x * 256 + threadIdx.x;   // 196*256 = 50176
  if (i < N_NODES) cnt[i] = 0;
  if (i < F * F) {
    int n = i >> 7;
    int k = i & 127;
    wt[n * 128 + k] = bf16rn(W[k * 128 + n]);
  }
  if (i < F) h[(size_t)N_NODES * F + i] = 0;       // sentinel zero row for agg1
  if (i == 0) { h2[2 * N_NODES] = 0.f; h2[2 * N_NODES + 1] = 0.f; }  // for agg2
}

// ---------- single-pass bucket fill: cnt doubles as degree + allocator ----------
__global__ __launch_bounds__(256) void k_fill(const int* __restrict__ ei, int* __restrict__ cnt,
                                              ushort* __restrict__ csr) {
  int e0 = (blockIdx.x * 256 + threadIdx.x) * 8;
  if (e0 >= N_EDGES) return;
  int4 sa = *(const int4*)&ei[e0];
  int4 sb = *(const int4*)&ei[e0 + 4];
  int4 da = *(const int4*)&ei[N_EDGES + e0];
  int4 db = *(const int4*)&ei[N_EDGES + e0 + 4];
  int p0 = atomicAdd(&cnt[da.x], 1);
  int p1 = atomicAdd(&cnt[da.y], 1);
  int p2 = atomicAdd(&cnt[da.z], 1);
  int p3 = atomicAdd(&cnt[da.w], 1);
  int p4 = atomicAdd(&cnt[db.x], 1);
  int p5 = atomicAdd(&cnt[db.y], 1);
  int p6 = atomicAdd(&cnt[db.z], 1);
  int p7 = atomicAdd(&cnt[db.w], 1);
  if (p0 < BCAP) csr[da.x * BCAP + p0] = (ushort)sa.x;
  if (p1 < BCAP) csr[da.y * BCAP + p1] = (ushort)sa.y;
  if (p2 < BCAP) csr[da.z * BCAP + p2] = (ushort)sa.z;
  if (p3 < BCAP) csr[da.w * BCAP + p3] = (ushort)sa.w;
  if (p4 < BCAP) csr[db.x * BCAP + p4] = (ushort)sb.x;
  if (p5 < BCAP) csr[db.y * BCAP + p5] = (ushort)sb.y;
  if (p6 < BCAP) csr[db.z * BCAP + p6] = (ushort)sb.z;
  if (p7 < BCAP) csr[db.w * BCAP + p7] = (ushort)sb.w;
}

// ---------- GEMM1 (MFMA, LDS-free) + fused nodeinit ----------
// h' = bf16(dinv[r] * (x @ W1)). No staging: every x element / wt fragment is
// consumed by exactly one lane, so A/B frags load straight from global
// (x: 16 fully-consumed 64B lines per wave-instruction; wt: L1-resident 32KB).
__global__ __launch_bounds__(256) void k_gemm1(const float* __restrict__ x, const ushort* __restrict__ wt_g,
                                               const int* __restrict__ cnt, float* __restrict__ dinv,
                                               ushort* __restrict__ csr, ushort* __restrict__ h) {
  __shared__ float dinv_lds[64];
  int t = threadIdx.x;
  int row0 = blockIdx.x * 64;

  // fused nodeinit for this block's 64 nodes
  if (t < 64) {
    int node = row0 + t;
    if (node < N_NODES) {
      int c = min(cnt[node], BCAP);
      float d = rsqrtf((float)(c + 1));
      dinv_lds[t] = d;
      dinv[node] = d;
      int npad = (c + 7) & ~7;
      for (int j = c; j < npad; ++j) csr[node * BCAP + j] = (ushort)N_NODES;
    }
  }

  int w = t >> 6;
  int lane = t & 63;
  int m = lane & 15;     // A row within wave tile / B col / C col
  int kb = lane >> 4;    // k sub-block 0..3 (8 bf16 each)
  int rloc = w * 16 + m;
  int grow = row0 + rloc;
  bool ok = grow < N_NODES;

  // A frags direct: row grow, cols ks*32 + kb*8 .. +7 (8 fp32 = 2 float4), cvt to bf16
  bf16x8 af[4];
  const float4* xrow = (const float4*)(x + (size_t)(ok ? grow : 0) * F);
  #pragma unroll
  for (int ks = 0; ks < 4; ++ks) {
    int c4 = ks * 8 + kb * 2;               // float4 index of first half
    float4 v0 = ok ? xrow[c4]     : make_float4(0.f, 0.f, 0.f, 0.f);
    float4 v1 = ok ? xrow[c4 + 1] : make_float4(0.f, 0.f, 0.f, 0.f);
    union { bf16x8 v; ushort s[8]; } fr;
    fr.s[0] = bf16rn(v0.x); fr.s[1] = bf16rn(v0.y); fr.s[2] = bf16rn(v0.z); fr.s[3] = bf16rn(v0.w);
    fr.s[4] = bf16rn(v1.x); fr.s[5] = bf16rn(v1.y); fr.s[6] = bf16rn(v1.z); fr.s[7] = bf16rn(v1.w);
    af[ks] = fr.v;
  }

  f32x4 acc[8];
  #pragma unroll
  for (int nf = 0; nf < 8; ++nf) acc[nf] = (f32x4){0.f, 0.f, 0.f, 0.f};

  // B frags direct from wt (bf16, [n][k]); per (nf,ks) the 4 kb-lanes of a col
  // cover one 64B line. wt = 32KB -> L1-hot after first pass.
  #pragma unroll
  for (int nf = 0; nf < 8; ++nf) {
    int ncol = nf * 16 + m;
    const bf16x8* wcol = (const bf16x8*)(wt_g + ncol * F + kb * 8);
    #pragma unroll
    for (int ks = 0; ks < 4; ++ks) {
      bf16x8 bfr = wcol[ks * 4];            // += ks*32 elements
      acc[nf] = __builtin_amdgcn_mfma_f32_16x16x32_bf16(af[ks], bfr, acc[nf], 0, 0, 0);
    }
  }

  __syncthreads();   // dinv_lds ready (covers the t<64 writes)

  // epilogue: C col = lane&15 (=m), row = kb*4 + reg
  int rbase = row0 + w * 16 + kb * 4;
  #pragma unroll
  for (int nf = 0; nf < 8; ++nf) {
    #pragma unroll
    for (int reg = 0; reg < 4; ++reg) {
      int rr = rbase + reg;
      if (rr < N_NODES) {
        float di = dinv_lds[w * 16 + kb * 4 + reg];
        h[(size_t)rr * F + nf * 16 + m] = bf16rn(di * acc[nf][reg]);
      }
    }
  }
}

// ---------- Fused agg1+gemm2: h2' = dinv * (relu(dinv*(h'[d]+sum h'[src]) + b1) @ W2) ----------
// 4 nodes per wave: 16 lanes/node, uint4 (8 bf16) per lane; x8 unroll with one uint4
// index load per iteration; sentinel-padded buckets -> no tail loop.
__global__ __launch_bounds__(256) void k_agg1(const uint4* __restrict__ h, const int* __restrict__ cnt,
                                              const float* __restrict__ dinv,
                                              const ushort* __restrict__ csr,
                                              const float* __restrict__ b1, const float* __restrict__ W2,
                                              float* __restrict__ h2) {
  int tid = threadIdx.x;
  int lane16 = tid & 15;                      // feature-octet index (features 8*lane16..+7)
  int node = blockIdx.x * 16 + (tid >> 4);    // grid = 3125 -> exactly 50000
  float di = dinv[node];
  uint4 su = h[(size_t)node * 16 + lane16];
  float a0 = bflo(su.x), a1 = bfhi(su.x), a2 = bflo(su.y), a3 = bfhi(su.y);
  float a4 = bflo(su.z), a5 = bfhi(su.z), a6 = bflo(su.w), a7 = bfhi(su.w);
  int base = node * BCAP;
  int npad = (min(cnt[node], BCAP) + 7) & ~7;
  for (int e = 0; e < npad; e += 8) {
    uint4 ci = *(const uint4*)&csr[base + e];   // 8 indices in one 16B load
    int s0 = ci.x & 0xFFFF, s1 = ci.x >> 16;
    int s2 = ci.y & 0xFFFF, s3 = ci.y >> 16;
    int s4 = ci.z & 0xFFFF, s5 = ci.z >> 16;
    int s6 = ci.w & 0xFFFF, s7 = ci.w >> 16;
    uint4 u0 = h[(size_t)s0 * 16 + lane16];
    uint4 u1 = h[(size_t)s1 * 16 + lane16];
    uint4 u2 = h[(size_t)s2 * 16 + lane16];
    uint4 u3 = h[(size_t)s3 * 16 + lane16];
    uint4 u4 = h[(size_t)s4 * 16 + lane16];
    uint4 u5 = h[(size_t)s5 * 16 + lane16];
    uint4 u6 = h[(size_t)s6 * 16 + lane16];
    uint4 u7 = h[(size_t)s7 * 16 + lane16];
    a0 += bflo(u0.x); a1 += bfhi(u0.x); a2 += bflo(u0.y); a3 += bfhi(u0.y);
    a4 += bflo(u0.z); a5 += bfhi(u0.z); a6 += bflo(u0.w); a7 += bfhi(u0.w);
    a0 += bflo(u1.x); a1 += bfhi(u1.x); a2 += bflo(u1.y); a3 += bfhi(u1.y);
    a4 += bflo(u1.z); a5 += bfhi(u1.z); a6 += bflo(u1.w); a7 += bfhi(u1.w);
    a0 += bflo(u2.x); a1 += bfhi(u2.x); a2 += bflo(u2.y); a3 += bfhi(u2.y);
    a4 += bflo(u2.z); a5 += bfhi(u2.z); a6 += bflo(u2.w); a7 += bfhi(u2.w);
    a0 += bflo(u3.x); a1 += bfhi(u3.x); a2 += bflo(u3.y); a3 += bfhi(u3.y);
    a4 += bflo(u3.z); a5 += bfhi(u3.z); a6 += bflo(u3.w); a7 += bfhi(u3.w);
    a0 += bflo(u4.x); a1 += bfhi(u4.x); a2 += bflo(u4.y); a3 += bfhi(u4.y);
    a4 += bflo(u4.z); a5 += bfhi(u4.z); a6 += bflo(u4.w); a7 += bfhi(u4.w);
    a0 += bflo(u5.x); a1 += bfhi(u5.x); a2 += bflo(u5.y); a3 += bfhi(u5.y);
    a4 += bflo(u5.z); a5 += bfhi(u5.z); a6 += bflo(u5.w); a7 += bfhi(u5.w);
    a0 += bflo(u6.x); a1 += bfhi(u6.x); a2 += bflo(u6.y); a3 += bfhi(u6.y);
    a4 += bflo(u6.z); a5 += bfhi(u6.z); a6 += bflo(u6.w); a7 += bfhi(u6.w);
    a0 += bflo(u7.x); a1 += bfhi(u7.x); a2 += bflo(u7.y); a3 += bfhi(u7.y);
    a4 += bflo(u7.z); a5 += bfhi(u7.z); a6 += bflo(u7.w); a7 += bfhi(u7.w);
  }
  float4 bb0 = ((const float4*)b1)[2 * lane16];
  float4 bb1 = ((const float4*)b1)[2 * lane16 + 1];
  float o0 = fmaxf(fmaf(di, a0, bb0.x), 0.f);
  float o1 = fmaxf(fmaf(di, a1, bb0.y), 0.f);
  float o2 = fmaxf(fmaf(di, a2, bb0.z), 0.f);
  float o3 = fmaxf(fmaf(di, a3, bb0.w), 0.f);
  float o4 = fmaxf(fmaf(di, a4, bb1.x), 0.f);
  float o5 = fmaxf(fmaf(di, a5, bb1.y), 0.f);
  float o6 = fmaxf(fmaf(di, a6, bb1.z), 0.f);
  float o7 = fmaxf(fmaf(di, a7, bb1.w), 0.f);

  // inline 128->2 GEMM: 8-feature partials, 4-step butterfly within 16-lane group
  const float2* W2v = (const float2*)W2;
  float2 w0 = W2v[8 * lane16 + 0], w1 = W2v[8 * lane16 + 1];
  float2 w2 = W2v[8 * lane16 + 2], w3 = W2v[8 * lane16 + 3];
  float2 w4 = W2v[8 * lane16 + 4], w5 = W2v[8 * lane16 + 5];
  float2 w6 = W2v[8 * lane16 + 6], w7 = W2v[8 * lane16 + 7];
  float c0 = fmaf(o0, w0.x, fmaf(o1, w1.x, fmaf(o2, w2.x, fmaf(o3, w3.x,
             fmaf(o4, w4.x, fmaf(o5, w5.x, fmaf(o6, w6.x, o7 * w7.x)))))));
  float c1 = fmaf(o0, w0.y, fmaf(o1, w1.y, fmaf(o2, w2.y, fmaf(o3, w3.y,
             fmaf(o4, w4.y, fmaf(o5, w5.y, fmaf(o6, w6.y, o7 * w7.y)))))));
  #pragma unroll
  for (int mask = 1; mask < 16; mask <<= 1) {
    c0 += __shfl_xor(c0, mask, 64);
    c1 += __shfl_xor(c1, mask, 64);
  }
  if (lane16 == 0) ((float2*)h2)[node] = make_float2(di * c0, di * c1);
}

// ---------- Aggregation 2: out = dinv[i]*(h2'[i] + sum h2'[src]) + b2 ----------
__global__ __launch_bounds__(256) void k_agg2(const float* __restrict__ h2, const int* __restrict__ cnt,
                                              const float* __restrict__ dinv,
                                              const ushort* __restrict__ csr,
                                              const float* __restrict__ b2, float* __restrict__ out) {
  int i = blockIdx.x * 256 + threadIdx.x;
  if (i >= N_NODES) return;
  float di = dinv[i];
  const float2* hp = (const float2*)h2;
  float2 self = hp[i];
  float ax = self.x;
  float ay = self.y;
  int base = i * BCAP;
  int npad = (min(cnt[i], BCAP) + 3) & ~3;   // sentinel pad covers to next mult of 8
  for (int e = 0; e < npad; e += 4) {
    uint2 ci = *(const uint2*)&csr[base + e];   // 4 indices in one 8B load
    int a = ci.x & 0xFFFF, b = ci.x >> 16;
    int c = ci.y & 0xFFFF, d = ci.y >> 16;
    float2 v0 = hp[a];
    float2 v1 = hp[b];
    float2 v2 = hp[c];
    float2 v3 = hp[d];
    ax += v0.x; ay += v0.y;
    ax += v1.x; ay += v1.y;
    ax += v2.x; ay += v2.y;
    ax += v3.x; ay += v3.y;
  }
  ((float2*)out)[i] = make_float2(fmaf(di, ax, b2[0]), fmaf(di, ay, b2[1]));
}

extern "C" void kernel_launch(void* const* d_in, const int* in_sizes, int n_in,
                              void* d_out, int out_size, void* d_ws, size_t ws_size,
                              hipStream_t stream) {
  const float* x  = (const float*)d_in[0];
  const int*   ei = (const int*)d_in[1];
  const float* W1 = (const float*)d_in[2];
  const float* b1 = (const float*)d_in[3];
  const float* W2 = (const float*)d_in[4];
  const float* b2 = (const float*)d_in[5];
  float* out = (float*)d_out;

  char* w = (char*)d_ws;
  auto alloc = [&](size_t bytes) {
    char* p = w;
    w += (bytes + 255) & ~size_t(255);
    return p;
  };
  int*    cnt  = (int*)alloc(N_NODES * 4);
  float*  dinv = (float*)alloc(N_NODES * 4);
  ushort* csr  = (ushort*)alloc((size_t)N_NODES * BCAP * 2);     // 6.4 MB buckets
  ushort* wt   = (ushort*)alloc((size_t)F * F * 2);              // W1^T in bf16
  ushort* h    = (ushort*)alloc((size_t)(N_NODES + 1) * F * 2);  // bf16 + zero row
  float*  h2   = (float*)alloc((size_t)(N_NODES + 1) * 2 * 4);   // + zero row

  k_init<<<196, 256, 0, stream>>>(cnt, W1, wt, h, h2);
  k_fill<<<293, 256, 0, stream>>>(ei, cnt, csr);
  k_gemm1<<<782, 256, 0, stream>>>(x, wt, cnt, dinv, csr, h);
  k_agg1<<<3125, 256, 0, stream>>>((const uint4*)h, cnt, dinv, csr, b1, W2, h2);
  k_agg2<<<196, 256, 0, stream>>>(h2, cnt, dinv, csr, b2, out);
}

// Round 11
// 89.991 us; speedup vs baseline: 1.0731x; 1.0731x over previous
//
#include <hip/hip_runtime.h>

#define N_NODES 50000
#define N_EDGES 600000
#define F 128
#define BCAP 64   // bucket capacity (max degree ~30 for Poisson(12))

typedef __attribute__((ext_vector_type(8))) short bf16x8;
typedef __attribute__((ext_vector_type(4))) float f32x4;

// bf16 helpers (round-to-nearest-even)
__device__ inline unsigned short bf16rn(float f) {
  unsigned u = __float_as_uint(f);
  return (unsigned short)((u + 0x7FFFu + ((u >> 16) & 1u)) >> 16);
}
__device__ inline float bflo(unsigned u) { return __uint_as_float(u << 16); }
__device__ inline float bfhi(unsigned u) { return __uint_as_float(u & 0xFFFF0000u); }

// ---------- init: zero cnt + W1 -> bf16 Wt[n][k] + zero sentinel rows ----------
__global__ __launch_bounds__(256) void k_init(int* __restrict__ cnt, const float* __restrict__ W,
                                              ushort* __restrict__ wt, ushort* __restrict__ h,
                                              float* __restrict__ h2) {
  int i = blockIdx.x * 256 + threadIdx.x;   // 196*256 = 50176
  if (i < N_NODES) cnt[i] = 0;
  if (i < F * F) {
    int n = i >> 7;
    int k = i & 127;
    wt[n * 128 + k] = bf16rn(W[k * 128 + n]);
  }
  if (i < F) h[(size_t)N_NODES * F + i] = 0;       // sentinel zero row for agg1
  if (i == 0) { h2[2 * N_NODES] = 0.f; h2[2 * N_NODES + 1] = 0.f; }  // for agg2
}

// ---------- single-pass bucket fill: cnt doubles as degree + allocator ----------
__global__ __launch_bounds__(256) void k_fill(const int* __restrict__ ei, int* __restrict__ cnt,
                                              ushort* __restrict__ csr) {
  int e0 = (blockIdx.x * 256 + threadIdx.x) * 8;
  if (e0 >= N_EDGES) return;
  int4 sa = *(const int4*)&ei[e0];
  int4 sb = *(const int4*)&ei[e0 + 4];
  int4 da = *(const int4*)&ei[N_EDGES + e0];
  int4 db = *(const int4*)&ei[N_EDGES + e0 + 4];
  int p0 = atomicAdd(&cnt[da.x], 1);
  int p1 = atomicAdd(&cnt[da.y], 1);
  int p2 = atomicAdd(&cnt[da.z], 1);
  int p3 = atomicAdd(&cnt[da.w], 1);
  int p4 = atomicAdd(&cnt[db.x], 1);
  int p5 = atomicAdd(&cnt[db.y], 1);
  int p6 = atomicAdd(&cnt[db.z], 1);
  int p7 = atomicAdd(&cnt[db.w], 1);
  if (p0 < BCAP) csr[da.x * BCAP + p0] = (ushort)sa.x;
  if (p1 < BCAP) csr[da.y * BCAP + p1] = (ushort)sa.y;
  if (p2 < BCAP) csr[da.z * BCAP + p2] = (ushort)sa.z;
  if (p3 < BCAP) csr[da.w * BCAP + p3] = (ushort)sa.w;
  if (p4 < BCAP) csr[db.x * BCAP + p4] = (ushort)sb.x;
  if (p5 < BCAP) csr[db.y * BCAP + p5] = (ushort)sb.y;
  if (p6 < BCAP) csr[db.z * BCAP + p6] = (ushort)sb.z;
  if (p7 < BCAP) csr[db.w * BCAP + p7] = (ushort)sb.w;
}

// ---------- GEMM1 (MFMA, LDS-staged) + fused nodeinit ----------
// h' = bf16(dinv[r] * (x @ W1)); also computes dinv for its 64 rows and
// sentinel-pads the csr buckets. LDS XOR-swizzled (byte^=(row&7)<<4).
__global__ __launch_bounds__(256) void k_gemm1(const float* __restrict__ x, const ushort* __restrict__ wt_g,
                                               const int* __restrict__ cnt, float* __restrict__ dinv,
                                               ushort* __restrict__ csr, ushort* __restrict__ h) {
  __shared__ ushort xs[64 * 128];
  __shared__ ushort wt[128 * 128];
  __shared__ float dinv_lds[64];
  int t = threadIdx.x;
  int row0 = blockIdx.x * 64;

  // fused nodeinit for this block's 64 nodes
  if (t < 64) {
    int node = row0 + t;
    if (node < N_NODES) {
      int c = min(cnt[node], BCAP);
      float d = rsqrtf((float)(c + 1));
      dinv_lds[t] = d;
      dinv[node] = d;
      int npad = (c + 7) & ~7;
      for (int j = c; j < npad; ++j) csr[node * BCAP + j] = (ushort)N_NODES;
    }
  }

  // stage x tile: thread t -> row r=t>>2, quarter q=t&3 (32 cols fp32 -> 32 bf16)
  {
    int r = t >> 2, q = t & 3;
    bool ok = (row0 + r) < N_NODES;
    const float4* xg = (const float4*)(x + (size_t)(row0 + r) * F + q * 32);
    unsigned pk[16];
    #pragma unroll
    for (int j = 0; j < 8; ++j) {
      float4 v = ok ? xg[j] : make_float4(0.f, 0.f, 0.f, 0.f);
      pk[2 * j]     = (unsigned)bf16rn(v.x) | ((unsigned)bf16rn(v.y) << 16);
      pk[2 * j + 1] = (unsigned)bf16rn(v.z) | ((unsigned)bf16rn(v.w) << 16);
    }
    #pragma unroll
    for (int j2 = 0; j2 < 4; ++j2) {
      int off = r * 256 + (((q * 64 + j2 * 16) ^ ((r & 7) << 4)));
      *(uint4*)((char*)xs + off) = make_uint4(pk[4 * j2], pk[4 * j2 + 1], pk[4 * j2 + 2], pk[4 * j2 + 3]);
    }
  }
  // stage Wt: thread t -> n=t>>1, half=t&1 (128B)
  {
    int n = t >> 1, hf = t & 1;
    const uint4* wg = (const uint4*)(wt_g + n * 128);
    #pragma unroll
    for (int j = 0; j < 8; ++j) {
      uint4 v = wg[hf * 8 + j];
      int off = n * 256 + (((hf * 128 + j * 16) ^ ((n & 7) << 4)));
      *(uint4*)((char*)wt + off) = v;
    }
  }
  __syncthreads();

  int w = t >> 6;
  int lane = t & 63;
  int m = lane & 15;
  int kb = lane >> 4;
  int rloc = w * 16 + m;

  bf16x8 af[4];
  #pragma unroll
  for (int ks = 0; ks < 4; ++ks) {
    int off = rloc * 256 + (((ks * 64 + kb * 16) ^ ((rloc & 7) << 4)));
    af[ks] = *(bf16x8*)((char*)xs + off);
  }

  f32x4 acc[8];
  #pragma unroll
  for (int nf = 0; nf < 8; ++nf) acc[nf] = (f32x4){0.f, 0.f, 0.f, 0.f};

  #pragma unroll
  for (int nf = 0; nf < 8; ++nf) {
    int ncol = nf * 16 + m;
    #pragma unroll
    for (int ks = 0; ks < 4; ++ks) {
      int off = ncol * 256 + (((ks * 64 + kb * 16) ^ ((ncol & 7) << 4)));
      bf16x8 bfr = *(bf16x8*)((char*)wt + off);
      acc[nf] = __builtin_amdgcn_mfma_f32_16x16x32_bf16(af[ks], bfr, acc[nf], 0, 0, 0);
    }
  }

  // epilogue: C col = lane&15 (=m), row = kb*4 + reg
  int rbase = row0 + w * 16 + kb * 4;
  #pragma unroll
  for (int nf = 0; nf < 8; ++nf) {
    #pragma unroll
    for (int reg = 0; reg < 4; ++reg) {
      int rr = rbase + reg;
      if (rr < N_NODES) {
        float di = dinv_lds[w * 16 + kb * 4 + reg];
        h[(size_t)rr * F + nf * 16 + m] = bf16rn(di * acc[nf][reg]);
      }
    }
  }
}

// ---------- Fused agg1+gemm2: h2' = dinv * (relu(dinv*(h'[d]+sum h'[src]) + b1) @ W2) ----------
// 4 nodes per wave: 16 lanes/node, uint4 (8 bf16) per lane; x8 unroll with one uint4
// index load per iteration; sentinel-padded buckets -> no tail loop.
__global__ __launch_bounds__(256) void k_agg1(const uint4* __restrict__ h, const int* __restrict__ cnt,
                                              const float* __restrict__ dinv,
                                              const ushort* __restrict__ csr,
                                              const float* __restrict__ b1, const float* __restrict__ W2,
                                              float* __restrict__ h2) {
  int tid = threadIdx.x;
  int lane16 = tid & 15;                      // feature-octet index (features 8*lane16..+7)
  int node = blockIdx.x * 16 + (tid >> 4);    // grid = 3125 -> exactly 50000
  float di = dinv[node];
  uint4 su = h[(size_t)node * 16 + lane16];
  float a0 = bflo(su.x), a1 = bfhi(su.x), a2 = bflo(su.y), a3 = bfhi(su.y);
  float a4 = bflo(su.z), a5 = bfhi(su.z), a6 = bflo(su.w), a7 = bfhi(su.w);
  int base = node * BCAP;
  int npad = (min(cnt[node], BCAP) + 7) & ~7;
  for (int e = 0; e < npad; e += 8) {
    uint4 ci = *(const uint4*)&csr[base + e];   // 8 indices in one 16B load
    int s0 = ci.x & 0xFFFF, s1 = ci.x >> 16;
    int s2 = ci.y & 0xFFFF, s3 = ci.y >> 16;
    int s4 = ci.z & 0xFFFF, s5 = ci.z >> 16;
    int s6 = ci.w & 0xFFFF, s7 = ci.w >> 16;
    uint4 u0 = h[(size_t)s0 * 16 + lane16];
    uint4 u1 = h[(size_t)s1 * 16 + lane16];
    uint4 u2 = h[(size_t)s2 * 16 + lane16];
    uint4 u3 = h[(size_t)s3 * 16 + lane16];
    uint4 u4 = h[(size_t)s4 * 16 + lane16];
    uint4 u5 = h[(size_t)s5 * 16 + lane16];
    uint4 u6 = h[(size_t)s6 * 16 + lane16];
    uint4 u7 = h[(size_t)s7 * 16 + lane16];
    a0 += bflo(u0.x); a1 += bfhi(u0.x); a2 += bflo(u0.y); a3 += bfhi(u0.y);
    a4 += bflo(u0.z); a5 += bfhi(u0.z); a6 += bflo(u0.w); a7 += bfhi(u0.w);
    a0 += bflo(u1.x); a1 += bfhi(u1.x); a2 += bflo(u1.y); a3 += bfhi(u1.y);
    a4 += bflo(u1.z); a5 += bfhi(u1.z); a6 += bflo(u1.w); a7 += bfhi(u1.w);
    a0 += bflo(u2.x); a1 += bfhi(u2.x); a2 += bflo(u2.y); a3 += bfhi(u2.y);
    a4 += bflo(u2.z); a5 += bfhi(u2.z); a6 += bflo(u2.w); a7 += bfhi(u2.w);
    a0 += bflo(u3.x); a1 += bfhi(u3.x); a2 += bflo(u3.y); a3 += bfhi(u3.y);
    a4 += bflo(u3.z); a5 += bfhi(u3.z); a6 += bflo(u3.w); a7 += bfhi(u3.w);
    a0 += bflo(u4.x); a1 += bfhi(u4.x); a2 += bflo(u4.y); a3 += bfhi(u4.y);
    a4 += bflo(u4.z); a5 += bfhi(u4.z); a6 += bflo(u4.w); a7 += bfhi(u4.w);
    a0 += bflo(u5.x); a1 += bfhi(u5.x); a2 += bflo(u5.y); a3 += bfhi(u5.y);
    a4 += bflo(u5.z); a5 += bfhi(u5.z); a6 += bflo(u5.w); a7 += bfhi(u5.w);
    a0 += bflo(u6.x); a1 += bfhi(u6.x); a2 += bflo(u6.y); a3 += bfhi(u6.y);
    a4 += bflo(u6.z); a5 += bfhi(u6.z); a6 += bflo(u6.w); a7 += bfhi(u6.w);
    a0 += bflo(u7.x); a1 += bfhi(u7.x); a2 += bflo(u7.y); a3 += bfhi(u7.y);
    a4 += bflo(u7.z); a5 += bfhi(u7.z); a6 += bflo(u7.w); a7 += bfhi(u7.w);
  }
  float4 bb0 = ((const float4*)b1)[2 * lane16];
  float4 bb1 = ((const float4*)b1)[2 * lane16 + 1];
  float o0 = fmaxf(fmaf(di, a0, bb0.x), 0.f);
  float o1 = fmaxf(fmaf(di, a1, bb0.y), 0.f);
  float o2 = fmaxf(fmaf(di, a2, bb0.z), 0.f);
  float o3 = fmaxf(fmaf(di, a3, bb0.w), 0.f);
  float o4 = fmaxf(fmaf(di, a4, bb1.x), 0.f);
  float o5 = fmaxf(fmaf(di, a5, bb1.y), 0.f);
  float o6 = fmaxf(fmaf(di, a6, bb1.z), 0.f);
  float o7 = fmaxf(fmaf(di, a7, bb1.w), 0.f);

  // inline 128->2 GEMM: 8-feature partials, 4-step butterfly within 16-lane group
  const float2* W2v = (const float2*)W2;
  float2 w0 = W2v[8 * lane16 + 0], w1 = W2v[8 * lane16 + 1];
  float2 w2 = W2v[8 * lane16 + 2], w3 = W2v[8 * lane16 + 3];
  float2 w4 = W2v[8 * lane16 + 4], w5 = W2v[8 * lane16 + 5];
  float2 w6 = W2v[8 * lane16 + 6], w7 = W2v[8 * lane16 + 7];
  float c0 = fmaf(o0, w0.x, fmaf(o1, w1.x, fmaf(o2, w2.x, fmaf(o3, w3.x,
             fmaf(o4, w4.x, fmaf(o5, w5.x, fmaf(o6, w6.x, o7 * w7.x)))))));
  float c1 = fmaf(o0, w0.y, fmaf(o1, w1.y, fmaf(o2, w2.y, fmaf(o3, w3.y,
             fmaf(o4, w4.y, fmaf(o5, w5.y, fmaf(o6, w6.y, o7 * w7.y)))))));
  #pragma unroll
  for (int mask = 1; mask < 16; mask <<= 1) {
    c0 += __shfl_xor(c0, mask, 64);
    c1 += __shfl_xor(c1, mask, 64);
  }
  if (lane16 == 0) ((float2*)h2)[node] = make_float2(di * c0, di * c1);
}

// ---------- Aggregation 2: out = dinv[i]*(h2'[i] + sum h2'[src]) + b2 ----------
__global__ __launch_bounds__(256) void k_agg2(const float* __restrict__ h2, const int* __restrict__ cnt,
                                              const float* __restrict__ dinv,
                                              const ushort* __restrict__ csr,
                                              const float* __restrict__ b2, float* __restrict__ out) {
  int i = blockIdx.x * 256 + threadIdx.x;
  if (i >= N_NODES) return;
  float di = dinv[i];
  const float2* hp = (const float2*)h2;
  float2 self = hp[i];
  float ax = self.x;
  float ay = self.y;
  int base = i * BCAP;
  int npad = (min(cnt[i], BCAP) + 3) & ~3;   // sentinel pad covers to next mult of 8
  for (int e = 0; e < npad; e += 4) {
    uint2 ci = *(const uint2*)&csr[base + e];   // 4 indices in one 8B load
    int a = ci.x & 0xFFFF, b = ci.x >> 16;
    int c = ci.y & 0xFFFF, d = ci.y >> 16;
    float2 v0 = hp[a];
    float2 v1 = hp[b];
    float2 v2 = hp[c];
    float2 v3 = hp[d];
    ax += v0.x; ay += v0.y;
    ax += v1.x; ay += v1.y;
    ax += v2.x; ay += v2.y;
    ax += v3.x; ay += v3.y;
  }
  ((float2*)out)[i] = make_float2(fmaf(di, ax, b2[0]), fmaf(di, ay, b2[1]));
}

extern "C" void kernel_launch(void* const* d_in, const int* in_sizes, int n_in,
                              void* d_out, int out_size, void* d_ws, size_t ws_size,
                              hipStream_t stream) {
  const float* x  = (const float*)d_in[0];
  const int*   ei = (const int*)d_in[1];
  const float* W1 = (const float*)d_in[2];
  const float* b1 = (const float*)d_in[3];
  const float* W2 = (const float*)d_in[4];
  const float* b2 = (const float*)d_in[5];
  float* out = (float*)d_out;

  char* w = (char*)d_ws;
  auto alloc = [&](size_t bytes) {
    char* p = w;
    w += (bytes + 255) & ~size_t(255);
    return p;
  };
  int*    cnt  = (int*)alloc(N_NODES * 4);
  float*  dinv = (float*)alloc(N_NODES * 4);
  ushort* csr  = (ushort*)alloc((size_t)N_NODES * BCAP * 2);     // 6.4 MB buckets
  ushort* wt   = (ushort*)alloc((size_t)F * F * 2);              // W1^T in bf16
  ushort* h    = (ushort*)alloc((size_t)(N_NODES + 1) * F * 2);  // bf16 + zero row
  float*  h2   = (float*)alloc((size_t)(N_NODES + 1) * 2 * 4);   // + zero row

  k_init<<<196, 256, 0, stream>>>(cnt, W1, wt, h, h2);
  k_fill<<<293, 256, 0, stream>>>(ei, cnt, csr);
  k_gemm1<<<782, 256, 0, stream>>>(x, wt, cnt, dinv, csr, h);
  k_agg1<<<3125, 256, 0, stream>>>((const uint4*)h, cnt, dinv, csr, b1, W2, h2);
  k_agg2<<<196, 256, 0, stream>>>(h2, cnt, dinv, csr, b2, out);
}